// Round 9
// baseline (123.584 us; speedup 1.0000x reference)
//
#include <hip/hip_runtime.h>
#include <math.h>

// QuanvolutionHybrid: conv2x2/s2 -> reshape(196,4) -> L2 norm ->
// all-pairs cos^2 >= 0.8 -> degree -> concat(784+196) -> linear(10) -> log_softmax
// One block = one batch element. VALU-issue-bound.
// R9: (a) fused SoA s_n[4][256] + FULL unroll of the 13-chunk pair loop ->
//     all 52 ds_read_b128 use immediate offsets off ONE base register
//     (R8 issue accounting: ~1850 insts/wave vs ~1100 semantic; addr math
//     was the gap). (b) LDS overlay: s_cnt/s_part/s_logits alias s_x
//     (dead after phase 2) -> 11.3 KB. (c) keep (256,6) + opaque pin.

#define NP 196
#define FEAT 980
#define COS_TH 0.894427190999915878f   // sqrt(0.8)

typedef float v2f __attribute__((ext_vector_type(2)));
typedef float v4f __attribute__((ext_vector_type(4)));

__global__ __launch_bounds__(256, 6) void quanv_kernel(
    const float* __restrict__ x,        // (8192, 784)
    const float* __restrict__ conv_w,   // (4,1,2,2) = 16
    const float* __restrict__ conv_b,   // (4,)
    const float* __restrict__ lin_w,    // (10, 980)
    const float* __restrict__ lin_b,    // (10,)
    float* __restrict__ out)            // (8192, 10)
{
    // s_x is dead after phase 2 -> overlay the small late-phase buffers on it.
    __shared__ __align__(16) float s_x[784];
    __shared__ __align__(16) float s_n[4][256];   // SoA planes x,y,z,w, zero-padded
    __shared__ __align__(16) float s_feats[FEAT];

    unsigned* s_cnt   = (unsigned*)s_x;           // [0,256)   uints
    float*    s_part  = s_x + 256;                // [256,512)
    float*    s_logits= s_x + 512;                // [512,522)

    const int b = blockIdx.x;
    const int t = threadIdx.x;
    const int w = t >> 6, l = t & 63;

    // ---- Phase 1: stage input image (coalesced float4) ----
    if (t < NP) {
        ((float4*)s_x)[t] = ((const float4*)(x + (size_t)b * 784))[t];
    }
    __syncthreads();

    // ---- Phase 2: 2x2/s2 conv -> flat[784] channel-major ----
    if (t < NP) {
        int h = t / 14, ww = t - 14 * (t / 14);
        const float* r0 = s_x + (2 * h) * 28 + 2 * ww;
        float x00 = r0[0], x01 = r0[1], x10 = r0[28], x11 = r0[29];
        #pragma unroll
        for (int c = 0; c < 4; ++c) {
            float f = conv_b[c]
                    + conv_w[c * 4 + 0] * x00 + conv_w[c * 4 + 1] * x01
                    + conv_w[c * 4 + 2] * x10 + conv_w[c * 4 + 3] * x11;
            s_feats[c * NP + t] = f;
        }
    }
    __syncthreads();   // also: s_x dead from here; overlays become usable

    // ---- Phase 3: normalize rows -> SoA planes (zero-padded to 256) ----
    if (t < NP) {
        float4 v = ((const float4*)s_feats)[t];
        float n = sqrtf(v.x * v.x + v.y * v.y + v.z * v.z + v.w * v.w);
        float inv = 1.0f / (n + 1e-12f);
        s_n[0][t] = v.x * inv; s_n[1][t] = v.y * inv;
        s_n[2][t] = v.z * inv; s_n[3][t] = v.w * inv;
    } else {
        s_n[0][t] = 0.f; s_n[1][t] = 0.f; s_n[2][t] = 0.f; s_n[3][t] = 0.f;
    }
    __syncthreads();

    // ---- Phase 4a: pair counts, rows {l, l+64, l+128};
    //      wave w sweeps q in [52w, 52w+52): 13 v4f chunks, ALL reads at
    //      immediate offsets (plane*1024 + j*16 bytes) off one base ptr. ----
    {
        v2f mx[3], my[3], mz[3], mw[3];
        #pragma unroll
        for (int r = 0; r < 3; ++r) {
            int row = l + 64 * r;
            float px = s_n[0][row], py = s_n[1][row], pz = s_n[2][row], pw = s_n[3][row];
            mx[r] = (v2f){px, px};
            my[r] = (v2f){py, py};
            mz[r] = (v2f){pz, pz};
            mw[r] = (v2f){pw, pw};
        }
        // Opaque pin: keeps the 12 broadcast pairs resident (no remat).
        #pragma unroll
        for (int r = 0; r < 3; ++r)
            asm("" : "+v"(mx[r]), "+v"(my[r]), "+v"(mz[r]), "+v"(mw[r]));

        unsigned cnt[3] = {0u, 0u, 0u};
        const float* qb = &s_n[0][52 * w];   // single base; planes at +256 floats
        #pragma unroll
        for (int j = 0; j < 13; ++j) {
            v4f qx = *(const v4f*)(qb + 4 * j);
            v4f qy = *(const v4f*)(qb + 256 + 4 * j);
            v4f qz = *(const v4f*)(qb + 512 + 4 * j);
            v4f qw = *(const v4f*)(qb + 768 + 4 * j);
            v2f qx0 = __builtin_shufflevector(qx, qx, 0, 1);
            v2f qx1 = __builtin_shufflevector(qx, qx, 2, 3);
            v2f qy0 = __builtin_shufflevector(qy, qy, 0, 1);
            v2f qy1 = __builtin_shufflevector(qy, qy, 2, 3);
            v2f qz0 = __builtin_shufflevector(qz, qz, 0, 1);
            v2f qz1 = __builtin_shufflevector(qz, qz, 2, 3);
            v2f qw0 = __builtin_shufflevector(qw, qw, 0, 1);
            v2f qw1 = __builtin_shufflevector(qw, qw, 2, 3);
            #pragma unroll
            for (int r = 0; r < 3; ++r) {
                v2f d0, d1;
                asm("v_pk_mul_f32 %0, %1, %2"     : "=v"(d0) : "v"(qx0), "v"(mx[r]));
                asm("v_pk_mul_f32 %0, %1, %2"     : "=v"(d1) : "v"(qx1), "v"(mx[r]));
                asm("v_pk_fma_f32 %0, %1, %2, %0" : "+v"(d0) : "v"(qy0), "v"(my[r]));
                asm("v_pk_fma_f32 %0, %1, %2, %0" : "+v"(d1) : "v"(qy1), "v"(my[r]));
                asm("v_pk_fma_f32 %0, %1, %2, %0" : "+v"(d0) : "v"(qz0), "v"(mz[r]));
                asm("v_pk_fma_f32 %0, %1, %2, %0" : "+v"(d1) : "v"(qz1), "v"(mz[r]));
                asm("v_pk_fma_f32 %0, %1, %2, %0" : "+v"(d0) : "v"(qw0), "v"(mw[r]));
                asm("v_pk_fma_f32 %0, %1, %2, %0" : "+v"(d1) : "v"(qw1), "v"(mw[r]));
                cnt[r] += (fabsf(d0.x) >= COS_TH);
                cnt[r] += (fabsf(d0.y) >= COS_TH);
                cnt[r] += (fabsf(d1.x) >= COS_TH);
                cnt[r] += (fabsf(d1.y) >= COS_TH);
            }
        }
        s_cnt[t] = cnt[0] | (cnt[1] << 8) | (cnt[2] << 16);
    }

    // ---- Phase 4b: tail rows 192..195, one per wave; lane l covers
    //      q = {l, 64+l, 128+l, 192+l} (zero-pad: q>=196 guaranteed miss) ----
    {
        int row = 192 + w;
        float px = s_n[0][row], py = s_n[1][row], pz = s_n[2][row], pw = s_n[3][row];
        unsigned total = 0u;
        #pragma unroll
        for (int j = 0; j < 4; ++j) {
            int q = 64 * j + l;
            float d = px * s_n[0][q];
            d = fmaf(py, s_n[1][q], d);
            d = fmaf(pz, s_n[2][q], d);
            d = fmaf(pw, s_n[3][q], d);
            unsigned long long m = __ballot(fabsf(d) >= COS_TH);
            total += (unsigned)__popcll(m);
        }
        if (l == 0) s_feats[784 + row] = (float)(total - 1u);  // self-edge
    }
    __syncthreads();

    // ---- Phase 5: cross-wave count sum -> degree feature (rows 0..191) ----
    if (t < 192) {
        int c = t >> 6, ll = t & 63;
        unsigned s = ((s_cnt[ll]       >> (8 * c)) & 255u)
                   + ((s_cnt[64 + ll]  >> (8 * c)) & 255u)
                   + ((s_cnt[128 + ll] >> (8 * c)) & 255u)
                   + ((s_cnt[192 + ll] >> (8 * c)) & 255u);
        s_feats[784 + t] = (float)(s - 1u);   // remove self-edge
    }
    __syncthreads();

    // ---- Phase 6: linear. t<250 -> (k=t/25, c=t%25), float4 dot over 980 ----
    if (t < 250) {
        int k = t / 25, c = t - 25 * (t / 25);
        const float4* wrow = (const float4*)(lin_w + k * FEAT);
        const float4* frow = (const float4*)s_feats;
        float acc = 0.0f;
        for (int i = c; i < 245; i += 25) {
            float4 f = frow[i];
            float4 wv = wrow[i];
            acc = fmaf(f.x, wv.x, acc);
            acc = fmaf(f.y, wv.y, acc);
            acc = fmaf(f.z, wv.z, acc);
            acc = fmaf(f.w, wv.w, acc);
        }
        s_part[t] = acc;
    }
    __syncthreads();

    if (t < 10) {
        float s = lin_b[t];
        #pragma unroll
        for (int i = 0; i < 25; ++i) s += s_part[t * 25 + i];
        s_logits[t] = s;
    }
    __syncthreads();

    // ---- Phase 7: log_softmax over 10 logits ----
    if (t < 10) {
        float m = -INFINITY;
        #pragma unroll
        for (int j = 0; j < 10; ++j) m = fmaxf(m, s_logits[j]);
        float s = 0.0f;
        #pragma unroll
        for (int j = 0; j < 10; ++j) s += expf(s_logits[j] - m);
        out[(size_t)b * 10 + t] = s_logits[t] - m - logf(s);
    }
}

extern "C" void kernel_launch(void* const* d_in, const int* in_sizes, int n_in,
                              void* d_out, int out_size, void* d_ws, size_t ws_size,
                              hipStream_t stream) {
    const float* x      = (const float*)d_in[0];
    const float* conv_w = (const float*)d_in[1];
    const float* conv_b = (const float*)d_in[2];
    const float* lin_w  = (const float*)d_in[3];
    const float* lin_b  = (const float*)d_in[4];
    float* out = (float*)d_out;
    quanv_kernel<<<dim3(8192), dim3(256), 0, stream>>>(x, conv_w, conv_b, lin_w, lin_b, out);
}

// Round 10
// 120.472 us; speedup vs baseline: 1.0258x; 1.0258x over previous
//
#include <hip/hip_runtime.h>
#include <math.h>

// QuanvolutionHybrid: conv2x2/s2 -> reshape(196,4) -> L2 norm ->
// all-pairs cos^2 >= 0.8 -> degree -> concat(784+196) -> linear(10) -> log_softmax
// R10: TWO images per block (grid 4096). R9 accounting: block lifetime ~20k cyc,
//      VALU issue only ~3.7k/wave -> 80% latency/barrier wait. Fusing 2 images
//      per barrier halves barrier+latency cost per image, doubles inter-barrier
//      ILP, and phase 6 shares each lin_w load across both images.

#define NP 196
#define FEAT 980
#define COS_TH 0.894427190999915878f   // sqrt(0.8)

typedef float v2f __attribute__((ext_vector_type(2)));
typedef float v4f __attribute__((ext_vector_type(4)));

__global__ __launch_bounds__(256, 6) void quanv_kernel(
    const float* __restrict__ x,        // (8192, 784)
    const float* __restrict__ conv_w,   // (4,1,2,2) = 16
    const float* __restrict__ conv_b,   // (4,)
    const float* __restrict__ lin_w,    // (10, 980)
    const float* __restrict__ lin_b,    // (10,)
    float* __restrict__ out)            // (8192, 10)
{
    // s_x[img] is dead after phase 2 -> overlay late-phase buffers on it.
    __shared__ __align__(16) float s_x[2][784];
    __shared__ __align__(16) float s_n[2][4][256];   // SoA planes, zero-padded
    __shared__ __align__(16) float s_feats[2][FEAT];

    const int b = blockIdx.x;            // 4096 blocks, 2 images each
    const int t = threadIdx.x;
    const int w = t >> 6, l = t & 63;

    // ---- Phase 1: stage both images (2 independent global streams) ----
    if (t < NP) {
        ((float4*)s_x[0])[t] = ((const float4*)(x + (size_t)(2 * b)     * 784))[t];
        ((float4*)s_x[1])[t] = ((const float4*)(x + (size_t)(2 * b + 1) * 784))[t];
    }
    __syncthreads();

    // ---- Phase 2: conv both ----
    if (t < NP) {
        int h = t / 14, ww = t - 14 * (t / 14);
        #pragma unroll
        for (int img = 0; img < 2; ++img) {
            const float* r0 = s_x[img] + (2 * h) * 28 + 2 * ww;
            float x00 = r0[0], x01 = r0[1], x10 = r0[28], x11 = r0[29];
            #pragma unroll
            for (int c = 0; c < 4; ++c) {
                float f = conv_b[c]
                        + conv_w[c * 4 + 0] * x00 + conv_w[c * 4 + 1] * x01
                        + conv_w[c * 4 + 2] * x10 + conv_w[c * 4 + 3] * x11;
                s_feats[img][c * NP + t] = f;
            }
        }
    }
    __syncthreads();   // s_x dead from here; overlays usable after this barrier

    // ---- Phase 3: normalize rows -> SoA planes (zero-padded) ----
    #pragma unroll
    for (int img = 0; img < 2; ++img) {
        if (t < NP) {
            float4 v = ((const float4*)s_feats[img])[t];
            float n = sqrtf(v.x * v.x + v.y * v.y + v.z * v.z + v.w * v.w);
            float inv = 1.0f / (n + 1e-12f);
            s_n[img][0][t] = v.x * inv; s_n[img][1][t] = v.y * inv;
            s_n[img][2][t] = v.z * inv; s_n[img][3][t] = v.w * inv;
        } else {
            s_n[img][0][t] = 0.f; s_n[img][1][t] = 0.f;
            s_n[img][2][t] = 0.f; s_n[img][3][t] = 0.f;
        }
    }
    __syncthreads();

    // ---- Phase 4: pair counts for both images (sequential, disjoint regs) ----
    #pragma unroll
    for (int img = 0; img < 2; ++img) {
        unsigned* s_cnt = (unsigned*)s_x[img];
        // rows {l, l+64, l+128}; wave w sweeps q in [52w, 52w+52)
        v2f mx[3], my[3], mz[3], mw[3];
        #pragma unroll
        for (int r = 0; r < 3; ++r) {
            int row = l + 64 * r;
            float px = s_n[img][0][row], py = s_n[img][1][row];
            float pz = s_n[img][2][row], pw = s_n[img][3][row];
            mx[r] = (v2f){px, px};
            my[r] = (v2f){py, py};
            mz[r] = (v2f){pz, pz};
            mw[r] = (v2f){pw, pw};
        }
        #pragma unroll
        for (int r = 0; r < 3; ++r)
            asm("" : "+v"(mx[r]), "+v"(my[r]), "+v"(mz[r]), "+v"(mw[r]));

        unsigned cnt[3] = {0u, 0u, 0u};
        const float* qb = &s_n[img][0][52 * w];   // planes at +256 floats
        #pragma unroll
        for (int j = 0; j < 13; ++j) {
            v4f qx = *(const v4f*)(qb + 4 * j);
            v4f qy = *(const v4f*)(qb + 256 + 4 * j);
            v4f qz = *(const v4f*)(qb + 512 + 4 * j);
            v4f qw = *(const v4f*)(qb + 768 + 4 * j);
            v2f qx0 = __builtin_shufflevector(qx, qx, 0, 1);
            v2f qx1 = __builtin_shufflevector(qx, qx, 2, 3);
            v2f qy0 = __builtin_shufflevector(qy, qy, 0, 1);
            v2f qy1 = __builtin_shufflevector(qy, qy, 2, 3);
            v2f qz0 = __builtin_shufflevector(qz, qz, 0, 1);
            v2f qz1 = __builtin_shufflevector(qz, qz, 2, 3);
            v2f qw0 = __builtin_shufflevector(qw, qw, 0, 1);
            v2f qw1 = __builtin_shufflevector(qw, qw, 2, 3);
            #pragma unroll
            for (int r = 0; r < 3; ++r) {
                v2f d0, d1;
                asm("v_pk_mul_f32 %0, %1, %2"     : "=v"(d0) : "v"(qx0), "v"(mx[r]));
                asm("v_pk_mul_f32 %0, %1, %2"     : "=v"(d1) : "v"(qx1), "v"(mx[r]));
                asm("v_pk_fma_f32 %0, %1, %2, %0" : "+v"(d0) : "v"(qy0), "v"(my[r]));
                asm("v_pk_fma_f32 %0, %1, %2, %0" : "+v"(d1) : "v"(qy1), "v"(my[r]));
                asm("v_pk_fma_f32 %0, %1, %2, %0" : "+v"(d0) : "v"(qz0), "v"(mz[r]));
                asm("v_pk_fma_f32 %0, %1, %2, %0" : "+v"(d1) : "v"(qz1), "v"(mz[r]));
                asm("v_pk_fma_f32 %0, %1, %2, %0" : "+v"(d0) : "v"(qw0), "v"(mw[r]));
                asm("v_pk_fma_f32 %0, %1, %2, %0" : "+v"(d1) : "v"(qw1), "v"(mw[r]));
                cnt[r] += (fabsf(d0.x) >= COS_TH);
                cnt[r] += (fabsf(d0.y) >= COS_TH);
                cnt[r] += (fabsf(d1.x) >= COS_TH);
                cnt[r] += (fabsf(d1.y) >= COS_TH);
            }
        }
        s_cnt[t] = cnt[0] | (cnt[1] << 8) | (cnt[2] << 16);

        // tail rows 192..195, one per wave; zero-pad makes q>=196 a miss
        int row = 192 + w;
        float px = s_n[img][0][row], py = s_n[img][1][row];
        float pz = s_n[img][2][row], pw = s_n[img][3][row];
        unsigned total = 0u;
        #pragma unroll
        for (int j = 0; j < 4; ++j) {
            int q = 64 * j + l;
            float d = px * s_n[img][0][q];
            d = fmaf(py, s_n[img][1][q], d);
            d = fmaf(pz, s_n[img][2][q], d);
            d = fmaf(pw, s_n[img][3][q], d);
            unsigned long long m = __ballot(fabsf(d) >= COS_TH);
            total += (unsigned)__popcll(m);
        }
        if (l == 0) s_feats[img][784 + row] = (float)(total - 1u);
    }
    __syncthreads();

    // ---- Phase 5: cross-wave count sum -> degree features (rows 0..191) ----
    if (t < 192) {
        int c = t >> 6, ll = t & 63;
        #pragma unroll
        for (int img = 0; img < 2; ++img) {
            const unsigned* s_cnt = (const unsigned*)s_x[img];
            unsigned s = ((s_cnt[ll]       >> (8 * c)) & 255u)
                       + ((s_cnt[64 + ll]  >> (8 * c)) & 255u)
                       + ((s_cnt[128 + ll] >> (8 * c)) & 255u)
                       + ((s_cnt[192 + ll] >> (8 * c)) & 255u);
            s_feats[img][784 + t] = (float)(s - 1u);
        }
    }
    __syncthreads();

    // ---- Phase 6: linear, shared lin_w loads across both images ----
    if (t < 250) {
        int k = t / 25, c = t - 25 * (t / 25);
        const float4* wrow = (const float4*)(lin_w + k * FEAT);
        const float4* f0p = (const float4*)s_feats[0];
        const float4* f1p = (const float4*)s_feats[1];
        float a0 = 0.0f, a1 = 0.0f;
        for (int i = c; i < 245; i += 25) {
            float4 wv = wrow[i];
            float4 f0 = f0p[i];
            float4 f1 = f1p[i];
            a0 = fmaf(f0.x, wv.x, a0); a1 = fmaf(f1.x, wv.x, a1);
            a0 = fmaf(f0.y, wv.y, a0); a1 = fmaf(f1.y, wv.y, a1);
            a0 = fmaf(f0.z, wv.z, a0); a1 = fmaf(f1.z, wv.z, a1);
            a0 = fmaf(f0.w, wv.w, a0); a1 = fmaf(f1.w, wv.w, a1);
        }
        (s_x[0] + 256)[t] = a0;    // s_part0
        (s_x[1] + 256)[t] = a1;    // s_part1
    }
    __syncthreads();

    if (t < 20) {
        int img = t / 10, k = t - 10 * (t / 10);
        const float* part = s_x[img] + 256;
        float s = lin_b[k];
        #pragma unroll
        for (int i = 0; i < 25; ++i) s += part[k * 25 + i];
        (s_x[img] + 512)[k] = s;   // s_logits
    }
    __syncthreads();

    // ---- Phase 7: log_softmax, both images in parallel lanes ----
    if (t < 20) {
        int img = t / 10, k = t - 10 * (t / 10);
        const float* lg = s_x[img] + 512;
        float m = -INFINITY;
        #pragma unroll
        for (int j = 0; j < 10; ++j) m = fmaxf(m, lg[j]);
        float s = 0.0f;
        #pragma unroll
        for (int j = 0; j < 10; ++j) s += expf(lg[j] - m);
        out[(size_t)(2 * b + img) * 10 + k] = lg[k] - m - logf(s);
    }
}

extern "C" void kernel_launch(void* const* d_in, const int* in_sizes, int n_in,
                              void* d_out, int out_size, void* d_ws, size_t ws_size,
                              hipStream_t stream) {
    const float* x      = (const float*)d_in[0];
    const float* conv_w = (const float*)d_in[1];
    const float* conv_b = (const float*)d_in[2];
    const float* lin_w  = (const float*)d_in[3];
    const float* lin_b  = (const float*)d_in[4];
    float* out = (float*)d_out;
    quanv_kernel<<<dim3(4096), dim3(256), 0, stream>>>(x, conv_w, conv_b, lin_w, lin_b, out);
}

// Round 11
// 120.180 us; speedup vs baseline: 1.0283x; 1.0024x over previous
//
#include <hip/hip_runtime.h>
#include <math.h>

// QuanvolutionHybrid: conv2x2/s2 -> reshape(196,4) -> L2 norm ->
// all-pairs cos^2 >= 0.8 -> degree -> concat(784+196) -> linear(10) -> log_softmax
// R11: R10 structure (2 images/block, grid 4096), but the pair-phase dot is
//      native v2f arithmetic (<2 x float> IR -> backend selects v_pk_fma_f32)
//      instead of per-statement inline asm. R8-R10 all pinned at ~63us with
//      ~3500 VALU insts/wave vs ~2100 semantic; the asm statement boundaries
//      (operand copies, sched barriers) are the suspected overhead.

#define NP 196
#define FEAT 980
#define COS_TH 0.894427190999915878f   // sqrt(0.8)

typedef float v2f __attribute__((ext_vector_type(2)));
typedef float v4f __attribute__((ext_vector_type(4)));

static __device__ __forceinline__ v2f pk_fma(v2f a, v2f b, v2f c) {
    return __builtin_elementwise_fma(a, b, c);
}

__global__ __launch_bounds__(256, 6) void quanv_kernel(
    const float* __restrict__ x,        // (8192, 784)
    const float* __restrict__ conv_w,   // (4,1,2,2) = 16
    const float* __restrict__ conv_b,   // (4,)
    const float* __restrict__ lin_w,    // (10, 980)
    const float* __restrict__ lin_b,    // (10,)
    float* __restrict__ out)            // (8192, 10)
{
    // s_x[img] is dead after phase 2 -> overlay late-phase buffers on it.
    __shared__ __align__(16) float s_x[2][784];
    __shared__ __align__(16) float s_n[2][4][256];   // SoA planes, zero-padded
    __shared__ __align__(16) float s_feats[2][FEAT];

    const int b = blockIdx.x;            // 4096 blocks, 2 images each
    const int t = threadIdx.x;
    const int w = t >> 6, l = t & 63;

    // ---- Phase 1: stage both images (2 independent global streams) ----
    if (t < NP) {
        ((float4*)s_x[0])[t] = ((const float4*)(x + (size_t)(2 * b)     * 784))[t];
        ((float4*)s_x[1])[t] = ((const float4*)(x + (size_t)(2 * b + 1) * 784))[t];
    }
    __syncthreads();

    // ---- Phase 2: conv both ----
    if (t < NP) {
        int h = t / 14, ww = t - 14 * (t / 14);
        #pragma unroll
        for (int img = 0; img < 2; ++img) {
            const float* r0 = s_x[img] + (2 * h) * 28 + 2 * ww;
            float x00 = r0[0], x01 = r0[1], x10 = r0[28], x11 = r0[29];
            #pragma unroll
            for (int c = 0; c < 4; ++c) {
                float f = conv_b[c]
                        + conv_w[c * 4 + 0] * x00 + conv_w[c * 4 + 1] * x01
                        + conv_w[c * 4 + 2] * x10 + conv_w[c * 4 + 3] * x11;
                s_feats[img][c * NP + t] = f;
            }
        }
    }
    __syncthreads();   // s_x dead from here; overlays usable after this barrier

    // ---- Phase 3: normalize rows -> SoA planes (zero-padded) ----
    #pragma unroll
    for (int img = 0; img < 2; ++img) {
        if (t < NP) {
            float4 v = ((const float4*)s_feats[img])[t];
            float n = sqrtf(v.x * v.x + v.y * v.y + v.z * v.z + v.w * v.w);
            float inv = 1.0f / (n + 1e-12f);
            s_n[img][0][t] = v.x * inv; s_n[img][1][t] = v.y * inv;
            s_n[img][2][t] = v.z * inv; s_n[img][3][t] = v.w * inv;
        } else {
            s_n[img][0][t] = 0.f; s_n[img][1][t] = 0.f;
            s_n[img][2][t] = 0.f; s_n[img][3][t] = 0.f;
        }
    }
    __syncthreads();

    // ---- Phase 4: pair counts for both images ----
    #pragma unroll
    for (int img = 0; img < 2; ++img) {
        unsigned* s_cnt = (unsigned*)s_x[img];
        // rows {l, l+64, l+128}; wave w sweeps q in [52w, 52w+52)
        v2f mx[3], my[3], mz[3], mw[3];
        #pragma unroll
        for (int r = 0; r < 3; ++r) {
            int row = l + 64 * r;
            float px = s_n[img][0][row], py = s_n[img][1][row];
            float pz = s_n[img][2][row], pw = s_n[img][3][row];
            mx[r] = (v2f){px, px};
            my[r] = (v2f){py, py};
            mz[r] = (v2f){pz, pz};
            mw[r] = (v2f){pw, pw};
        }
        // One-time pin: keep the 12 broadcast pairs resident (anti-remat, R5).
        #pragma unroll
        for (int r = 0; r < 3; ++r)
            asm("" : "+v"(mx[r]), "+v"(my[r]), "+v"(mz[r]), "+v"(mw[r]));

        unsigned cnt[3] = {0u, 0u, 0u};
        const float* qb = &s_n[img][0][52 * w];   // planes at +256 floats
        #pragma unroll
        for (int j = 0; j < 13; ++j) {
            v4f qx = *(const v4f*)(qb + 4 * j);
            v4f qy = *(const v4f*)(qb + 256 + 4 * j);
            v4f qz = *(const v4f*)(qb + 512 + 4 * j);
            v4f qw = *(const v4f*)(qb + 768 + 4 * j);
            v2f qx0 = __builtin_shufflevector(qx, qx, 0, 1);
            v2f qx1 = __builtin_shufflevector(qx, qx, 2, 3);
            v2f qy0 = __builtin_shufflevector(qy, qy, 0, 1);
            v2f qy1 = __builtin_shufflevector(qy, qy, 2, 3);
            v2f qz0 = __builtin_shufflevector(qz, qz, 0, 1);
            v2f qz1 = __builtin_shufflevector(qz, qz, 2, 3);
            v2f qw0 = __builtin_shufflevector(qw, qw, 0, 1);
            v2f qw1 = __builtin_shufflevector(qw, qw, 2, 3);
            #pragma unroll
            for (int r = 0; r < 3; ++r) {
                v2f d0 = qx0 * mx[r];
                v2f d1 = qx1 * mx[r];
                d0 = pk_fma(qy0, my[r], d0);
                d1 = pk_fma(qy1, my[r], d1);
                d0 = pk_fma(qz0, mz[r], d0);
                d1 = pk_fma(qz1, mz[r], d1);
                d0 = pk_fma(qw0, mw[r], d0);
                d1 = pk_fma(qw1, mw[r], d1);
                cnt[r] += (fabsf(d0.x) >= COS_TH);
                cnt[r] += (fabsf(d0.y) >= COS_TH);
                cnt[r] += (fabsf(d1.x) >= COS_TH);
                cnt[r] += (fabsf(d1.y) >= COS_TH);
            }
        }
        s_cnt[t] = cnt[0] | (cnt[1] << 8) | (cnt[2] << 16);

        // tail rows 192..195, one per wave; zero-pad makes q>=196 a miss
        int row = 192 + w;
        float px = s_n[img][0][row], py = s_n[img][1][row];
        float pz = s_n[img][2][row], pw = s_n[img][3][row];
        unsigned total = 0u;
        #pragma unroll
        for (int j = 0; j < 4; ++j) {
            int q = 64 * j + l;
            float d = px * s_n[img][0][q];
            d = fmaf(py, s_n[img][1][q], d);
            d = fmaf(pz, s_n[img][2][q], d);
            d = fmaf(pw, s_n[img][3][q], d);
            unsigned long long m = __ballot(fabsf(d) >= COS_TH);
            total += (unsigned)__popcll(m);
        }
        if (l == 0) s_feats[img][784 + row] = (float)(total - 1u);
    }
    __syncthreads();

    // ---- Phase 5: cross-wave count sum -> degree features (rows 0..191) ----
    if (t < 192) {
        int c = t >> 6, ll = t & 63;
        #pragma unroll
        for (int img = 0; img < 2; ++img) {
            const unsigned* s_cnt = (const unsigned*)s_x[img];
            unsigned s = ((s_cnt[ll]       >> (8 * c)) & 255u)
                       + ((s_cnt[64 + ll]  >> (8 * c)) & 255u)
                       + ((s_cnt[128 + ll] >> (8 * c)) & 255u)
                       + ((s_cnt[192 + ll] >> (8 * c)) & 255u);
            s_feats[img][784 + t] = (float)(s - 1u);
        }
    }
    __syncthreads();

    // ---- Phase 6: linear, shared lin_w loads across both images ----
    if (t < 250) {
        int k = t / 25, c = t - 25 * (t / 25);
        const float4* wrow = (const float4*)(lin_w + k * FEAT);
        const float4* f0p = (const float4*)s_feats[0];
        const float4* f1p = (const float4*)s_feats[1];
        float a0 = 0.0f, a1 = 0.0f;
        for (int i = c; i < 245; i += 25) {
            float4 wv = wrow[i];
            float4 f0 = f0p[i];
            float4 f1 = f1p[i];
            a0 = fmaf(f0.x, wv.x, a0); a1 = fmaf(f1.x, wv.x, a1);
            a0 = fmaf(f0.y, wv.y, a0); a1 = fmaf(f1.y, wv.y, a1);
            a0 = fmaf(f0.z, wv.z, a0); a1 = fmaf(f1.z, wv.z, a1);
            a0 = fmaf(f0.w, wv.w, a0); a1 = fmaf(f1.w, wv.w, a1);
        }
        (s_x[0] + 256)[t] = a0;    // s_part0
        (s_x[1] + 256)[t] = a1;    // s_part1
    }
    __syncthreads();

    if (t < 20) {
        int img = t / 10, k = t - 10 * (t / 10);
        const float* part = s_x[img] + 256;
        float s = lin_b[k];
        #pragma unroll
        for (int i = 0; i < 25; ++i) s += part[k * 25 + i];
        (s_x[img] + 512)[k] = s;   // s_logits
    }
    __syncthreads();

    // ---- Phase 7: log_softmax, both images in parallel lanes ----
    if (t < 20) {
        int img = t / 10, k = t - 10 * (t / 10);
        const float* lg = s_x[img] + 512;
        float m = -INFINITY;
        #pragma unroll
        for (int j = 0; j < 10; ++j) m = fmaxf(m, lg[j]);
        float s = 0.0f;
        #pragma unroll
        for (int j = 0; j < 10; ++j) s += expf(lg[j] - m);
        out[(size_t)(2 * b + img) * 10 + k] = lg[k] - m - logf(s);
    }
}

extern "C" void kernel_launch(void* const* d_in, const int* in_sizes, int n_in,
                              void* d_out, int out_size, void* d_ws, size_t ws_size,
                              hipStream_t stream) {
    const float* x      = (const float*)d_in[0];
    const float* conv_w = (const float*)d_in[1];
    const float* conv_b = (const float*)d_in[2];
    const float* lin_w  = (const float*)d_in[3];
    const float* lin_b  = (const float*)d_in[4];
    float* out = (float*)d_out;
    quanv_kernel<<<dim3(4096), dim3(256), 0, stream>>>(x, conv_w, conv_b, lin_w, lin_b, out);
}

// Round 12
// 120.053 us; speedup vs baseline: 1.0294x; 1.0011x over previous
//
#include <hip/hip_runtime.h>
#include <math.h>

// QuanvolutionHybrid: conv2x2/s2 -> reshape(196,4) -> L2 norm ->
// all-pairs cos^2 >= 0.8 -> degree -> concat(784+196) -> linear(10) -> log_softmax
// R12: R11 structure (2 images/block, native pk MACs) + fused count asm:
//      4x v_cmp_le_f32_e64 (abs mod, distinct sgpr pairs - no vcc serialization)
//      + 4x v_addc_co_u32_e64 (sgpr carry) alternating two accumulators.
//      Guarantees 2 insts/dot for counting vs compiler's ~3 (cndmask path).

#define NP 196
#define FEAT 980
#define COS_TH 0.894427190999915878f   // sqrt(0.8)

typedef float v2f __attribute__((ext_vector_type(2)));
typedef float v4f __attribute__((ext_vector_type(4)));

static __device__ __forceinline__ v2f pk_fma(v2f a, v2f b, v2f c) {
    return __builtin_elementwise_fma(a, b, c);
}

__global__ __launch_bounds__(256, 6) void quanv_kernel(
    const float* __restrict__ x,        // (8192, 784)
    const float* __restrict__ conv_w,   // (4,1,2,2) = 16
    const float* __restrict__ conv_b,   // (4,)
    const float* __restrict__ lin_w,    // (10, 980)
    const float* __restrict__ lin_b,    // (10,)
    float* __restrict__ out)            // (8192, 10)
{
    // s_x[img] is dead after phase 2 -> overlay late-phase buffers on it.
    __shared__ __align__(16) float s_x[2][784];
    __shared__ __align__(16) float s_n[2][4][256];   // SoA planes, zero-padded
    __shared__ __align__(16) float s_feats[2][FEAT];

    const int b = blockIdx.x;            // 4096 blocks, 2 images each
    const int t = threadIdx.x;
    const int w = t >> 6, l = t & 63;

    // ---- Phase 1: stage both images (2 independent global streams) ----
    if (t < NP) {
        ((float4*)s_x[0])[t] = ((const float4*)(x + (size_t)(2 * b)     * 784))[t];
        ((float4*)s_x[1])[t] = ((const float4*)(x + (size_t)(2 * b + 1) * 784))[t];
    }
    __syncthreads();

    // ---- Phase 2: conv both ----
    if (t < NP) {
        int h = t / 14, ww = t - 14 * (t / 14);
        #pragma unroll
        for (int img = 0; img < 2; ++img) {
            const float* r0 = s_x[img] + (2 * h) * 28 + 2 * ww;
            float x00 = r0[0], x01 = r0[1], x10 = r0[28], x11 = r0[29];
            #pragma unroll
            for (int c = 0; c < 4; ++c) {
                float f = conv_b[c]
                        + conv_w[c * 4 + 0] * x00 + conv_w[c * 4 + 1] * x01
                        + conv_w[c * 4 + 2] * x10 + conv_w[c * 4 + 3] * x11;
                s_feats[img][c * NP + t] = f;
            }
        }
    }
    __syncthreads();   // s_x dead from here; overlays usable after this barrier

    // ---- Phase 3: normalize rows -> SoA planes (zero-padded) ----
    #pragma unroll
    for (int img = 0; img < 2; ++img) {
        if (t < NP) {
            float4 v = ((const float4*)s_feats[img])[t];
            float n = sqrtf(v.x * v.x + v.y * v.y + v.z * v.z + v.w * v.w);
            float inv = 1.0f / (n + 1e-12f);
            s_n[img][0][t] = v.x * inv; s_n[img][1][t] = v.y * inv;
            s_n[img][2][t] = v.z * inv; s_n[img][3][t] = v.w * inv;
        } else {
            s_n[img][0][t] = 0.f; s_n[img][1][t] = 0.f;
            s_n[img][2][t] = 0.f; s_n[img][3][t] = 0.f;
        }
    }
    __syncthreads();

    float vth = COS_TH;
    asm("" : "+v"(vth));   // keep threshold resident in one VGPR

    // ---- Phase 4: pair counts for both images ----
    #pragma unroll
    for (int img = 0; img < 2; ++img) {
        unsigned* s_cnt = (unsigned*)s_x[img];
        // rows {l, l+64, l+128}; wave w sweeps q in [52w, 52w+52)
        v2f mx[3], my[3], mz[3], mw[3];
        #pragma unroll
        for (int r = 0; r < 3; ++r) {
            int row = l + 64 * r;
            float px = s_n[img][0][row], py = s_n[img][1][row];
            float pz = s_n[img][2][row], pw = s_n[img][3][row];
            mx[r] = (v2f){px, px};
            my[r] = (v2f){py, py};
            mz[r] = (v2f){pz, pz};
            mw[r] = (v2f){pw, pw};
        }
        // One-time pin: keep the 12 broadcast pairs resident (anti-remat, R5).
        #pragma unroll
        for (int r = 0; r < 3; ++r)
            asm("" : "+v"(mx[r]), "+v"(my[r]), "+v"(mz[r]), "+v"(mw[r]));

        unsigned cA[3] = {0u, 0u, 0u}, cB[3] = {0u, 0u, 0u};
        const float* qb = &s_n[img][0][52 * w];   // planes at +256 floats
        #pragma unroll
        for (int j = 0; j < 13; ++j) {
            v4f qx = *(const v4f*)(qb + 4 * j);
            v4f qy = *(const v4f*)(qb + 256 + 4 * j);
            v4f qz = *(const v4f*)(qb + 512 + 4 * j);
            v4f qw = *(const v4f*)(qb + 768 + 4 * j);
            v2f qx0 = __builtin_shufflevector(qx, qx, 0, 1);
            v2f qx1 = __builtin_shufflevector(qx, qx, 2, 3);
            v2f qy0 = __builtin_shufflevector(qy, qy, 0, 1);
            v2f qy1 = __builtin_shufflevector(qy, qy, 2, 3);
            v2f qz0 = __builtin_shufflevector(qz, qz, 0, 1);
            v2f qz1 = __builtin_shufflevector(qz, qz, 2, 3);
            v2f qw0 = __builtin_shufflevector(qw, qw, 0, 1);
            v2f qw1 = __builtin_shufflevector(qw, qw, 2, 3);
            #pragma unroll
            for (int r = 0; r < 3; ++r) {
                v2f d0 = qx0 * mx[r];
                v2f d1 = qx1 * mx[r];
                d0 = pk_fma(qy0, my[r], d0);
                d1 = pk_fma(qy1, my[r], d1);
                d0 = pk_fma(qz0, mz[r], d0);
                d1 = pk_fma(qz1, mz[r], d1);
                d0 = pk_fma(qw0, mw[r], d0);
                d1 = pk_fma(qw1, mw[r], d1);
                unsigned long long sa, sb, sc, sd;
                asm("v_cmp_le_f32_e64 %2, %6, |%7|\n\t"
                    "v_cmp_le_f32_e64 %3, %6, |%8|\n\t"
                    "v_cmp_le_f32_e64 %4, %6, |%9|\n\t"
                    "v_cmp_le_f32_e64 %5, %6, |%10|\n\t"
                    "v_addc_co_u32_e64 %0, %2, %0, 0, %2\n\t"
                    "v_addc_co_u32_e64 %1, %3, %1, 0, %3\n\t"
                    "v_addc_co_u32_e64 %0, %4, %0, 0, %4\n\t"
                    "v_addc_co_u32_e64 %1, %5, %1, 0, %5"
                    : "+v"(cA[r]), "+v"(cB[r]),
                      "=&s"(sa), "=&s"(sb), "=&s"(sc), "=&s"(sd)
                    : "v"(vth), "v"(d0.x), "v"(d0.y), "v"(d1.x), "v"(d1.y));
            }
        }
        unsigned cnt0 = cA[0] + cB[0];
        unsigned cnt1 = cA[1] + cB[1];
        unsigned cnt2 = cA[2] + cB[2];
        s_cnt[t] = cnt0 | (cnt1 << 8) | (cnt2 << 16);

        // tail rows 192..195, one per wave; zero-pad makes q>=196 a miss
        int row = 192 + w;
        float px = s_n[img][0][row], py = s_n[img][1][row];
        float pz = s_n[img][2][row], pw = s_n[img][3][row];
        unsigned total = 0u;
        #pragma unroll
        for (int j = 0; j < 4; ++j) {
            int q = 64 * j + l;
            float d = px * s_n[img][0][q];
            d = fmaf(py, s_n[img][1][q], d);
            d = fmaf(pz, s_n[img][2][q], d);
            d = fmaf(pw, s_n[img][3][q], d);
            unsigned long long m = __ballot(fabsf(d) >= COS_TH);
            total += (unsigned)__popcll(m);
        }
        if (l == 0) s_feats[img][784 + row] = (float)(total - 1u);
    }
    __syncthreads();

    // ---- Phase 5: cross-wave count sum -> degree features (rows 0..191) ----
    if (t < 192) {
        int c = t >> 6, ll = t & 63;
        #pragma unroll
        for (int img = 0; img < 2; ++img) {
            const unsigned* s_cnt = (const unsigned*)s_x[img];
            unsigned s = ((s_cnt[ll]       >> (8 * c)) & 255u)
                       + ((s_cnt[64 + ll]  >> (8 * c)) & 255u)
                       + ((s_cnt[128 + ll] >> (8 * c)) & 255u)
                       + ((s_cnt[192 + ll] >> (8 * c)) & 255u);
            s_feats[img][784 + t] = (float)(s - 1u);
        }
    }
    __syncthreads();

    // ---- Phase 6: linear, shared lin_w loads across both images ----
    if (t < 250) {
        int k = t / 25, c = t - 25 * (t / 25);
        const float4* wrow = (const float4*)(lin_w + k * FEAT);
        const float4* f0p = (const float4*)s_feats[0];
        const float4* f1p = (const float4*)s_feats[1];
        float a0 = 0.0f, a1 = 0.0f;
        for (int i = c; i < 245; i += 25) {
            float4 wv = wrow[i];
            float4 f0 = f0p[i];
            float4 f1 = f1p[i];
            a0 = fmaf(f0.x, wv.x, a0); a1 = fmaf(f1.x, wv.x, a1);
            a0 = fmaf(f0.y, wv.y, a0); a1 = fmaf(f1.y, wv.y, a1);
            a0 = fmaf(f0.z, wv.z, a0); a1 = fmaf(f1.z, wv.z, a1);
            a0 = fmaf(f0.w, wv.w, a0); a1 = fmaf(f1.w, wv.w, a1);
        }
        (s_x[0] + 256)[t] = a0;    // s_part0
        (s_x[1] + 256)[t] = a1;    // s_part1
    }
    __syncthreads();

    if (t < 20) {
        int img = t / 10, k = t - 10 * (t / 10);
        const float* part = s_x[img] + 256;
        float s = lin_b[k];
        #pragma unroll
        for (int i = 0; i < 25; ++i) s += part[k * 25 + i];
        (s_x[img] + 512)[k] = s;   // s_logits
    }
    __syncthreads();

    // ---- Phase 7: log_softmax, both images in parallel lanes ----
    if (t < 20) {
        int img = t / 10, k = t - 10 * (t / 10);
        const float* lg = s_x[img] + 512;
        float m = -INFINITY;
        #pragma unroll
        for (int j = 0; j < 10; ++j) m = fmaxf(m, lg[j]);
        float s = 0.0f;
        #pragma unroll
        for (int j = 0; j < 10; ++j) s += expf(lg[j] - m);
        out[(size_t)(2 * b + img) * 10 + k] = lg[k] - m - logf(s);
    }
}

extern "C" void kernel_launch(void* const* d_in, const int* in_sizes, int n_in,
                              void* d_out, int out_size, void* d_ws, size_t ws_size,
                              hipStream_t stream) {
    const float* x      = (const float*)d_in[0];
    const float* conv_w = (const float*)d_in[1];
    const float* conv_b = (const float*)d_in[2];
    const float* lin_w  = (const float*)d_in[3];
    const float* lin_b  = (const float*)d_in[4];
    float* out = (float*)d_out;
    quanv_kernel<<<dim3(4096), dim3(256), 0, stream>>>(x, conv_w, conv_b, lin_w, lin_b, out);
}

// Round 14
// 109.462 us; speedup vs baseline: 1.1290x; 1.0968x over previous
//
#include <hip/hip_runtime.h>
#include <math.h>

// QuanvolutionHybrid: conv2x2/s2 -> reshape(196,4) -> L2 norm ->
// all-pairs cos^2 >= 0.8 -> degree -> concat(784+196) -> linear(10) -> log_softmax
// R14: R13's MFMA pair phase, de-risked. R13 failed with cnt==0 underflow
//      (absmax 3.7e8 = 4.29e9 * 0.02 * few) => NaN/garbage accumulators from
//      codegen-level constructs, not layout (packing is provably mapping-
//      invariant). Changes: (a) no unions - s_P is short[][8], operands via
//      vector pointer loads + shufflevector; (b) no inline asm in phase 4 -
//      plain C counting; (c) (float)(int)cnt-1.0f underflow guard.

#define NP 196
#define FEAT 980
#define COS_TH 0.894427190999915878f   // sqrt(0.8)

typedef short v4s  __attribute__((ext_vector_type(4)));
typedef short v8s  __attribute__((ext_vector_type(8)));
typedef float v16f __attribute__((ext_vector_type(16)));

__global__ __launch_bounds__(256, 6) void quanv_kernel(
    const float* __restrict__ x,        // (8192, 784)
    const float* __restrict__ conv_w,   // (4,1,2,2) = 16
    const float* __restrict__ conv_b,   // (4,)
    const float* __restrict__ lin_w,    // (10, 980)
    const float* __restrict__ lin_b,    // (10,)
    float* __restrict__ out)            // (8192, 10)
{
    // s_x[img] dead after phase 2 -> late-phase overlays live on it.
    __shared__ __align__(16) float s_x[2][784];
    __shared__ __align__(16) short s_P[2][224][8];  // bf16 row: h0..h3, l0..l3
    __shared__ __align__(16) float s_feats[2][FEAT];

    const int b = blockIdx.x;            // 4096 blocks, 2 images each
    const int t = threadIdx.x;
    const int w = t >> 6, l = t & 63;

    // ---- Phase 1: stage both images ----
    if (t < NP) {
        ((float4*)s_x[0])[t] = ((const float4*)(x + (size_t)(2 * b)     * 784))[t];
        ((float4*)s_x[1])[t] = ((const float4*)(x + (size_t)(2 * b + 1) * 784))[t];
    }
    __syncthreads();

    // ---- Phase 2: conv both -> s_feats[img][0..784) channel-major ----
    if (t < NP) {
        int h = t / 14, ww = t - 14 * (t / 14);
        #pragma unroll
        for (int img = 0; img < 2; ++img) {
            const float* r0 = s_x[img] + (2 * h) * 28 + 2 * ww;
            float x00 = r0[0], x01 = r0[1], x10 = r0[28], x11 = r0[29];
            #pragma unroll
            for (int c = 0; c < 4; ++c) {
                float f = conv_b[c]
                        + conv_w[c * 4 + 0] * x00 + conv_w[c * 4 + 1] * x01
                        + conv_w[c * 4 + 2] * x10 + conv_w[c * 4 + 3] * x11;
                s_feats[img][c * NP + t] = f;
            }
        }
    }
    __syncthreads();   // s_x dead; overlays usable after this barrier

    // ---- Phase 3: normalize + exact bf16 hi/lo split -> s_P (rows 196..223 = 0) ----
    if (t < 224) {
        #pragma unroll
        for (int img = 0; img < 2; ++img) {
            v8s pk = {0, 0, 0, 0, 0, 0, 0, 0};
            if (t < NP) {
                float4 v = ((const float4*)s_feats[img])[t];
                float n = sqrtf(v.x * v.x + v.y * v.y + v.z * v.z + v.w * v.w);
                float inv = 1.0f / (n + 1e-12f);
                float e[4] = { v.x * inv, v.y * inv, v.z * inv, v.w * inv };
                #pragma unroll
                for (int k = 0; k < 4; ++k) {
                    uint32_t bx = __float_as_uint(e[k]);
                    uint32_t rh = bx + 0x7FFFu + ((bx >> 16) & 1u);   // RNE bf16
                    uint32_t hk = rh >> 16;
                    float hif = __uint_as_float(hk << 16);
                    float res = e[k] - hif;                            // exact
                    uint32_t br = __float_as_uint(res);
                    uint32_t rl = br + 0x7FFFu + ((br >> 16) & 1u);
                    pk[k]     = (short)hk;
                    pk[4 + k] = (short)(rl >> 16);
                }
            }
            *(v8s*)&s_P[img][t][0] = pk;
        }
    }
    __syncthreads();

    // ---- Phase 4: 14 jobs = (img, col-stripe j); wave takes jobs w, w+4, ...
    // A k-pack [h0..h3,l0..l3]; B half0 [h0..h3 x2], half1 [l0..l3 x2]
    // => contraction = exact (h+l).(h+l), invariant to k<->(half,j) mapping.
    for (int job = w; job < 14; job += 4) {
        const int img = (job >= 7) ? 1 : 0;
        const int j = job - 7 * img;
        const int ln = l & 31, half = l >> 5;

        v4s bh = *(const v4s*)&s_P[img][32 * j + ln][4 * half];
        v8s B = __builtin_shufflevector(bh, bh, 0, 1, 2, 3, 0, 1, 2, 3);

        v8s A[7];
        #pragma unroll
        for (int i = 0; i < 7; ++i)
            A[i] = *(const v8s*)&s_P[img][32 * i + ln][0];

        unsigned cnt = 0u;
        #pragma unroll
        for (int i = 0; i < 7; ++i) {
            v16f acc = {0.f,0.f,0.f,0.f,0.f,0.f,0.f,0.f,
                        0.f,0.f,0.f,0.f,0.f,0.f,0.f,0.f};
            acc = __builtin_amdgcn_mfma_f32_32x32x16_bf16(A[i], B, acc, 0, 0, 0);
            #pragma unroll
            for (int e = 0; e < 16; ++e)
                cnt += (fabsf(acc[e]) >= COS_TH) ? 1u : 0u;
        }
        cnt += __shfl_down(cnt, 32, 64);   // merge the two row-halves
        if (l < 32) {
            int col = 32 * j + l;
            if (col < NP)
                s_feats[img][784 + col] = (float)(int)cnt - 1.0f;  // self-edge
        }
    }
    __syncthreads();

    // ---- Phase 5: linear, shared lin_w loads across both images ----
    if (t < 250) {
        int k = t / 25, c = t - 25 * (t / 25);
        const float4* wrow = (const float4*)(lin_w + k * FEAT);
        const float4* f0p = (const float4*)s_feats[0];
        const float4* f1p = (const float4*)s_feats[1];
        float a0 = 0.0f, a1 = 0.0f;
        for (int i = c; i < 245; i += 25) {
            float4 wv = wrow[i];
            float4 f0 = f0p[i];
            float4 f1 = f1p[i];
            a0 = fmaf(f0.x, wv.x, a0); a1 = fmaf(f1.x, wv.x, a1);
            a0 = fmaf(f0.y, wv.y, a0); a1 = fmaf(f1.y, wv.y, a1);
            a0 = fmaf(f0.z, wv.z, a0); a1 = fmaf(f1.z, wv.z, a1);
            a0 = fmaf(f0.w, wv.w, a0); a1 = fmaf(f1.w, wv.w, a1);
        }
        (s_x[0] + 256)[t] = a0;    // s_part0 (overlay)
        (s_x[1] + 256)[t] = a1;    // s_part1 (overlay)
    }
    __syncthreads();

    if (t < 20) {
        int img = t / 10, k = t - 10 * (t / 10);
        const float* part = s_x[img] + 256;
        float s = lin_b[k];
        #pragma unroll
        for (int i = 0; i < 25; ++i) s += part[k * 25 + i];
        (s_x[img] + 512)[k] = s;   // s_logits (overlay)
    }
    __syncthreads();

    // ---- Phase 6: log_softmax, both images in parallel lanes ----
    if (t < 20) {
        int img = t / 10, k = t - 10 * (t / 10);
        const float* lg = s_x[img] + 512;
        float m = -INFINITY;
        #pragma unroll
        for (int j2 = 0; j2 < 10; ++j2) m = fmaxf(m, lg[j2]);
        float s = 0.0f;
        #pragma unroll
        for (int j2 = 0; j2 < 10; ++j2) s += expf(lg[j2] - m);
        out[(size_t)(2 * b + img) * 10 + k] = lg[k] - m - logf(s);
    }
}

extern "C" void kernel_launch(void* const* d_in, const int* in_sizes, int n_in,
                              void* d_out, int out_size, void* d_ws, size_t ws_size,
                              hipStream_t stream) {
    const float* x      = (const float*)d_in[0];
    const float* conv_w = (const float*)d_in[1];
    const float* conv_b = (const float*)d_in[2];
    const float* lin_w  = (const float*)d_in[3];
    const float* lin_b  = (const float*)d_in[4];
    float* out = (float*)d_out;
    quanv_kernel<<<dim3(4096), dim3(256), 0, stream>>>(x, conv_w, conv_b, lin_w, lin_b, out);
}